// Round 8
// baseline (635.224 us; speedup 1.0000x reference)
//
#include <hip/hip_runtime.h>

// Problem constants
#define NB 10000          // batch
#define NC 64             // channels
#define NROWS (NB * NC)   // 640000 (b,c) rows
#define NE 10             // elements
#define DIN 40            // 1+3+9+27
#define NM 13             // 1+3+9 output m's
#define NPAIR 820         // 40*41/2 symmetric pairs (fallback layout)
#define NBAND4 10         // i-bands of 4 (primary layout)
#define NSTEP4 220        // sum_b (40-4b)
#define XS 41             // LDS row stride

#define XT_FLOATS (DIN * NROWS)                       // 25,600,000
#define PACK4_FLOATS (NSTEP4 * 64 + DIN * 16)         // 14,720
#define WS_NEED_BYTES ((size_t)(XT_FLOATS + PACK4_FLOATS) * 4)

// ---------------------------------------------------------------------------
// Pack (primary): band-4 layout. Step e <-> (band b of 4 rows, col j), with
// offset(b) = 2b(21-b), j = 4b + (e - offset(b)), j in [4b, 39].
// Entry = 64 floats: 4 pair-slots x 16; slot t holds coefs for pair
// (i=4b+t, j), x2 off-diagonal, ZERO when i>j or m>=13.  u1Pack [40][16]
// follows (layout unchanged).
// ---------------------------------------------------------------------------
__global__ void psc_pack4_kernel(const float* __restrict__ U2_0,
                                 const float* __restrict__ U2_1,
                                 const float* __restrict__ U2_2,
                                 const float* __restrict__ U1_0,
                                 const float* __restrict__ U1_1,
                                 const float* __restrict__ U1_2,
                                 float* __restrict__ coefPack,   // [220][64]
                                 float* __restrict__ u1Pack)     // [40][16]
{
    int tid = blockIdx.x * blockDim.x + threadIdx.x;
    if (tid < NSTEP4 * 64) {
        int e = tid >> 6, s = tid & 63;
        int t = s >> 4, m = s & 15;
        int b = 0;
        while (b < NBAND4 - 1 && 2 * (b + 1) * (20 - b) <= e) ++b;
        int j = 4 * b + (e - 2 * b * (21 - b));
        int i = 4 * b + t;
        float v = 0.0f;
        if (m < NM && i <= j) {
            float sc = (i == j) ? 1.0f : 2.0f;
            if (m == 0)      v = U2_0[i * 40 + j] * sc;
            else if (m < 4)  v = U2_1[(m - 1) * 1600 + i * 40 + j] * sc;
            else             v = U2_2[(m - 4) * 1600 + i * 40 + j] * sc;
        }
        coefPack[tid] = v;
    } else if (tid < NSTEP4 * 64 + DIN * 16) {
        int t = tid - NSTEP4 * 64;
        int m = t & 15;
        int i = t >> 4;
        float v = 0.0f;
        if (m == 0)       v = U1_0[i];
        else if (m < 4)   v = U1_1[(m - 1) * 40 + i];
        else if (m < 13)  v = U1_2[(m - 4) * 40 + i];
        u1Pack[i * 16 + m] = v;
    }
}

// ---------------------------------------------------------------------------
// Transpose (primary): LDS-tiled, coalesced reads AND writes.
// One block = one b (64 channels x 40 comps). Read pattern proven in R3/R4.
// ---------------------------------------------------------------------------
__global__ __launch_bounds__(256)
void psc_transpose2_kernel(const float* __restrict__ f0,
                           const float* __restrict__ f1,
                           const float* __restrict__ f2,
                           const float* __restrict__ f3,
                           float* __restrict__ xT)
{
    __shared__ float ls[64 * XS];     // 10.5 KB
    const int t = threadIdx.x;
    const int b = blockIdx.x;

    if (t < 64)  ls[t * XS + 0] = f0[b * 64 + t];
    if (t < 192) { int c = t / 3, k = t % 3; ls[c * XS + 1 + k] = f1[b * 192 + t]; }
    for (int idx = t; idx < 576; idx += 256) {
        int c = idx / 9, k = idx % 9;
        ls[c * XS + 4 + k] = f2[b * 576 + idx];
    }
    for (int idx = t; idx < 1728; idx += 256) {
        int c = idx / 27, k = idx % 27;
        ls[c * XS + 13 + k] = f3[b * 1728 + idx];
    }
    __syncthreads();

    const int c = t & 63, j0 = t >> 6;
    #pragma unroll
    for (int jj = 0; jj < 10; ++jj) {
        int j = j0 + jj * 4;
        xT[j * NROWS + b * 64 + c] = ls[c * XS + j];   // stride-41 LDS read: conflict-free
    }
}

// 13 FMAs into acc2[R][*] from 4 float4 coefficient regs (wave-uniform)
#define FMA13Q(R, Q0, Q1, Q2, Q3, XX)                                   \
    acc2[R][0]  += (Q0).x * (XX);  acc2[R][1]  += (Q0).y * (XX);        \
    acc2[R][2]  += (Q0).z * (XX);  acc2[R][3]  += (Q0).w * (XX);        \
    acc2[R][4]  += (Q1).x * (XX);  acc2[R][5]  += (Q1).y * (XX);        \
    acc2[R][6]  += (Q1).z * (XX);  acc2[R][7]  += (Q1).w * (XX);        \
    acc2[R][8]  += (Q2).x * (XX);  acc2[R][9]  += (Q2).y * (XX);        \
    acc2[R][10] += (Q2).z * (XX);  acc2[R][11] += (Q2).w * (XX);        \
    acc2[R][12] += (Q3).x * (XX);

#define A1FMA(R, Q0, Q1, Q2, Q3, XI)                                    \
    a1[R][0]  += (Q0).x * (XI);  a1[R][1]  += (Q0).y * (XI);            \
    a1[R][2]  += (Q0).z * (XI);  a1[R][3]  += (Q0).w * (XI);            \
    a1[R][4]  += (Q1).x * (XI);  a1[R][5]  += (Q1).y * (XI);            \
    a1[R][6]  += (Q1).z * (XI);  a1[R][7]  += (Q1).w * (XI);            \
    a1[R][8]  += (Q2).x * (XI);  a1[R][9]  += (Q2).y * (XI);            \
    a1[R][10] += (Q2).z * (XI);  a1[R][11] += (Q2).w * (XI);            \
    a1[R][12] += (Q3).x * (XI);

// ---------------------------------------------------------------------------
// Main (primary): band-4, plain rolled loop (compiler-scheduled), fused
// per-row epilogue. Block = 128 threads = 2 waves; wave owns 128 rows
// (2 b's, R=2 rows/lane). Per inner step: 2 per-lane x_j loads (512 B/wave)
// + 16 wave-uniform coef float4s (scalarized) serve 104 FMAs.
// LDS: per-wave 13x64 f32 basis buffer (6656 B total) -> no barriers at all.
// ---------------------------------------------------------------------------
__global__ __launch_bounds__(128, 6)
void psc_main_b4(const float* __restrict__ xT,
                 const float* __restrict__ attrs,
                 const float* __restrict__ W1_0, const float* __restrict__ W2_0,
                 const float* __restrict__ Wlin_0, const float* __restrict__ sc_0,
                 const float* __restrict__ W1_1, const float* __restrict__ W2_1,
                 const float* __restrict__ Wlin_1, const float* __restrict__ sc_1,
                 const float* __restrict__ W1_2, const float* __restrict__ W2_2,
                 const float* __restrict__ Wlin_2, const float* __restrict__ sc_2,
                 const float* __restrict__ coefPack,
                 const float* __restrict__ u1Pack,
                 float* __restrict__ out)
{
    __shared__ float bsT[2][NM][64];          // per-wave row buffer, 6656 B

    const int lane = threadIdx.x & 63;
    const int wid  = threadIdx.x >> 6;
    const int bc0  = blockIdx.x * 256 + wid * 128;  // wave's first row

    float acc2[2][NM], a1[2][NM];
    #pragma unroll
    for (int m = 0; m < NM; ++m) {
        acc2[0][m] = 0.f; acc2[1][m] = 0.f;
        a1[0][m] = 0.f;   a1[1][m] = 0.f;
    }

    const float4* cp4 = (const float4*)coefPack;
    const float4* u14 = (const float4*)u1Pack;

    for (int b4 = 0; b4 < NBAND4; ++b4) {
        const int i0 = 4 * b4;

        // band xi registers (4 i-rows x 2 b-rows)
        const float* xip = xT + i0 * NROWS + bc0;
        float xi00 = xip[lane], xi01 = xip[lane + 64]; xip += NROWS;
        float xi10 = xip[lane], xi11 = xip[lane + 64]; xip += NROWS;
        float xi20 = xip[lane], xi21 = xip[lane + 64]; xip += NROWS;
        float xi30 = xip[lane], xi31 = xip[lane + 64];

        // fold a1 for this band's 4 i-rows (uniform u1 loads)
        {
            const float4* u = u14 + i0 * 4;
            float4 u0 = u[0],  u1 = u[1],  u2 = u[2],  u3 = u[3];
            A1FMA(0, u0, u1, u2, u3, xi00);  A1FMA(1, u0, u1, u2, u3, xi01);
            u0 = u[4];  u1 = u[5];  u2 = u[6];  u3 = u[7];
            A1FMA(0, u0, u1, u2, u3, xi10);  A1FMA(1, u0, u1, u2, u3, xi11);
            u0 = u[8];  u1 = u[9];  u2 = u[10]; u3 = u[11];
            A1FMA(0, u0, u1, u2, u3, xi20);  A1FMA(1, u0, u1, u2, u3, xi21);
            u0 = u[12]; u1 = u[13]; u2 = u[14]; u3 = u[15];
            A1FMA(0, u0, u1, u2, u3, xi30);  A1FMA(1, u0, u1, u2, u3, xi31);
        }

        // inner j loop: plain, compiler-scheduled
        const float* xjp = xT + i0 * NROWS + bc0;
        for (int j = i0; j < DIN; ++j) {
            float xj0 = xjp[lane];
            float xj1 = xjp[lane + 64];
            xjp += NROWS;
            float4 q0  = cp4[0],  q1  = cp4[1],  q2  = cp4[2],  q3  = cp4[3];
            float4 q4  = cp4[4],  q5  = cp4[5],  q6  = cp4[6],  q7  = cp4[7];
            float4 q8  = cp4[8],  q9  = cp4[9],  q10 = cp4[10], q11 = cp4[11];
            float4 q12 = cp4[12], q13 = cp4[13], q14 = cp4[14], q15 = cp4[15];
            cp4 += 16;

            float xx00 = xi00 * xj0, xx01 = xi01 * xj1;
            float xx10 = xi10 * xj0, xx11 = xi11 * xj1;
            float xx20 = xi20 * xj0, xx21 = xi21 * xj1;
            float xx30 = xi30 * xj0, xx31 = xi31 * xj1;

            FMA13Q(0, q0,  q1,  q2,  q3,  xx00);
            FMA13Q(1, q0,  q1,  q2,  q3,  xx01);
            FMA13Q(0, q4,  q5,  q6,  q7,  xx10);
            FMA13Q(1, q4,  q5,  q6,  q7,  xx11);
            FMA13Q(0, q8,  q9,  q10, q11, xx20);
            FMA13Q(1, q8,  q9,  q10, q11, xx21);
            FMA13Q(0, q12, q13, q14, q15, xx30);
            FMA13Q(1, q12, q13, q14, q15, xx31);
        }
    }

    // ---- per-row epilogue: w-weights, basis -> per-wave LDS, mix, write ----
    #pragma unroll
    for (int r = 0; r < 2; ++r) {
        const int br = (bc0 >> 6) + r;

        float w10 = 0.f, w20 = 0.f, w11 = 0.f, w21 = 0.f, w12 = 0.f, w22 = 0.f;
        #pragma unroll
        for (int e = 0; e < NE; ++e) {
            float av = attrs[br * NE + e];       // wave-uniform -> s_load
            w10 += av * W1_0[e * 64 + lane];
            w20 += av * W2_0[e * 64 + lane];
            w11 += av * W1_1[e * 64 + lane];
            w21 += av * W2_1[e * 64 + lane];
            w12 += av * W1_2[e * 64 + lane];
            w22 += av * W2_2[e * 64 + lane];
        }

        bsT[wid][0][lane] = a1[r][0] * w10 + acc2[r][0] * w20;
        #pragma unroll
        for (int m = 1; m < 4; ++m)
            bsT[wid][m][lane] = a1[r][m] * w11 + acc2[r][m] * w21;
        #pragma unroll
        for (int m = 4; m < NM; ++m)
            bsT[wid][m][lane] = a1[r][m] * w12 + acc2[r][m] * w22;
        // wave-private buffer: in-order DS pipe + compiler lgkmcnt, no barrier

        float om[NM];
        #pragma unroll
        for (int m = 0; m < NM; ++m) om[m] = 0.f;

        for (int c4 = 0; c4 < 16; ++c4) {
            const int cc = c4 * 4;
            float p0 = Wlin_0[(cc + 0) * 64 + lane], p1 = Wlin_0[(cc + 1) * 64 + lane],
                  p2 = Wlin_0[(cc + 2) * 64 + lane], p3 = Wlin_0[(cc + 3) * 64 + lane];
            float q0 = Wlin_1[(cc + 0) * 64 + lane], q1 = Wlin_1[(cc + 1) * 64 + lane],
                  q2 = Wlin_1[(cc + 2) * 64 + lane], q3 = Wlin_1[(cc + 3) * 64 + lane];
            float r0 = Wlin_2[(cc + 0) * 64 + lane], r1 = Wlin_2[(cc + 1) * 64 + lane],
                  r2 = Wlin_2[(cc + 2) * 64 + lane], r3 = Wlin_2[(cc + 3) * 64 + lane];

            float4 tv;
            tv = *(const float4*)&bsT[wid][0][cc];   // uniform -> broadcast
            om[0] += tv.x * p0 + tv.y * p1 + tv.z * p2 + tv.w * p3;
            #pragma unroll
            for (int m = 1; m < 4; ++m) {
                tv = *(const float4*)&bsT[wid][m][cc];
                om[m] += tv.x * q0 + tv.y * q1 + tv.z * q2 + tv.w * q3;
            }
            #pragma unroll
            for (int m = 4; m < NM; ++m) {
                tv = *(const float4*)&bsT[wid][m][cc];
                om[m] += tv.x * r0 + tv.y * r1 + tv.z * r2 + tv.w * r3;
            }
        }

        const int bo = bc0 + r * 64 + lane;     // == b*64 + c
        out[bo] = om[0] + sc_0[bo];
        #pragma unroll
        for (int k = 0; k < 3; ++k)
            out[NROWS + bo * 3 + k] = om[1 + k] + sc_1[bo * 3 + k];
        #pragma unroll
        for (int k = 0; k < 9; ++k)
            out[NROWS * 4 + bo * 9 + k] = om[4 + k] + sc_2[bo * 9 + k];
    }
}

// ---------------------------------------------------------------------------
// Fallback path (proven 438 us, measured R4): old pack layout + LDS-staged x.
// ---------------------------------------------------------------------------
__global__ void psc_pack_kernel(const float* __restrict__ U2_0,
                                const float* __restrict__ U2_1,
                                const float* __restrict__ U2_2,
                                const float* __restrict__ U1_0,
                                const float* __restrict__ U1_1,
                                const float* __restrict__ U1_2,
                                float* __restrict__ coefPack,   // [820][16]
                                float* __restrict__ u1Pack)     // [40][16]
{
    int tid = blockIdx.x * blockDim.x + threadIdx.x;
    if (tid < 1600 * 16) {
        int m = tid & 15;
        int idx = tid >> 4;
        int i = idx / 40, j = idx % 40;
        if (j < i) return;
        int p = i * 40 - ((i * (i - 1)) >> 1) + (j - i);
        float s = (i == j) ? 1.0f : 2.0f;
        float v = 0.0f;
        if (m == 0)       v = U2_0[i * 40 + j];
        else if (m < 4)   v = U2_1[(m - 1) * 1600 + i * 40 + j];
        else if (m < 13)  v = U2_2[(m - 4) * 1600 + i * 40 + j];
        coefPack[p * 16 + m] = v * s;
    } else if (tid < 1600 * 16 + 40 * 16) {
        int t = tid - 1600 * 16;
        int m = t & 15;
        int i = t >> 4;
        float v = 0.0f;
        if (m == 0)       v = U1_0[i];
        else if (m < 4)   v = U1_1[(m - 1) * 40 + i];
        else if (m < 13)  v = U1_2[(m - 4) * 40 + i];
        u1Pack[i * 16 + m] = v;
    }
}

#define FMA13(Q0, Q1, Q2, Q3, XX)                                     \
    acc2[0]  += (Q0).x * (XX);  acc2[1]  += (Q0).y * (XX);            \
    acc2[2]  += (Q0).z * (XX);  acc2[3]  += (Q0).w * (XX);            \
    acc2[4]  += (Q1).x * (XX);  acc2[5]  += (Q1).y * (XX);            \
    acc2[6]  += (Q1).z * (XX);  acc2[7]  += (Q1).w * (XX);            \
    acc2[8]  += (Q2).x * (XX);  acc2[9]  += (Q2).y * (XX);            \
    acc2[10] += (Q2).z * (XX);  acc2[11] += (Q2).w * (XX);            \
    acc2[12] += (Q3).x * (XX);

#define ADV()                                                         \
    do {                                                              \
        ++jp;                                                         \
        if (jp >= DIN) {                                              \
            if (ip < DIN - 1) ++ip;                                   \
            jp = ip;                                                  \
            xip = xrow[ip];                                           \
        }                                                             \
    } while (0)

__global__ __launch_bounds__(64, 4)
void psc_main_lds(const float* __restrict__ f0, const float* __restrict__ f1,
                  const float* __restrict__ f2, const float* __restrict__ f3,
                  const float* __restrict__ attrs,
                  const float* __restrict__ W1_0, const float* __restrict__ W2_0,
                  const float* __restrict__ Wlin_0, const float* __restrict__ sc_0,
                  const float* __restrict__ W1_1, const float* __restrict__ W2_1,
                  const float* __restrict__ Wlin_1, const float* __restrict__ sc_1,
                  const float* __restrict__ W1_2, const float* __restrict__ W2_2,
                  const float* __restrict__ Wlin_2, const float* __restrict__ sc_2,
                  const float* __restrict__ coefPack,
                  const float* __restrict__ u1Pack,
                  float* __restrict__ out)
{
    __shared__ float xs[64 * XS];

    const int c = threadIdx.x;
    const int b = blockIdx.x;

    xs[c * XS + 0] = f0[b * 64 + c];
    #pragma unroll
    for (int t = 0; t < 3; ++t) {
        int idx = c + 64 * t;
        int cc = idx / 3, k = idx % 3;
        xs[cc * XS + 1 + k] = f1[b * 192 + idx];
    }
    #pragma unroll
    for (int t = 0; t < 9; ++t) {
        int idx = c + 64 * t;
        int cc = idx / 9, k = idx % 9;
        xs[cc * XS + 4 + k] = f2[b * 576 + idx];
    }
    #pragma unroll
    for (int t = 0; t < 27; ++t) {
        int idx = c + 64 * t;
        int cc = idx / 27, k = idx % 27;
        xs[cc * XS + 13 + k] = f3[b * 1728 + idx];
    }
    __syncthreads();

    float w1l0 = 0.f, w2l0 = 0.f, w1l1 = 0.f, w2l1 = 0.f, w1l2 = 0.f, w2l2 = 0.f;
    #pragma unroll
    for (int e = 0; e < NE; ++e) {
        float a = attrs[b * NE + e];
        w1l0 += a * W1_0[e * 64 + c];
        w2l0 += a * W2_0[e * 64 + c];
        w1l1 += a * W1_1[e * 64 + c];
        w2l1 += a * W2_1[e * 64 + c];
        w1l2 += a * W1_2[e * 64 + c];
        w2l2 += a * W2_2[e * 64 + c];
    }

    const float* xrow = &xs[c * XS];

    float acc1[NM];
    #pragma unroll
    for (int m = 0; m < NM; ++m) acc1[m] = 0.f;
    #pragma unroll 4
    for (int i = 0; i < DIN; ++i) {
        float xi = xrow[i];
        const float4* u4 = (const float4*)&u1Pack[i * 16];
        float4 u0 = u4[0], u1v = u4[1], u2v = u4[2], u3v = u4[3];
        acc1[0]  += u0.x  * xi;  acc1[1]  += u0.y  * xi;
        acc1[2]  += u0.z  * xi;  acc1[3]  += u0.w  * xi;
        acc1[4]  += u1v.x * xi;  acc1[5]  += u1v.y * xi;
        acc1[6]  += u1v.z * xi;  acc1[7]  += u1v.w * xi;
        acc1[8]  += u2v.x * xi;  acc1[9]  += u2v.y * xi;
        acc1[10] += u2v.z * xi;  acc1[11] += u2v.w * xi;
        acc1[12] += u3v.x * xi;
    }

    float acc2[NM];
    #pragma unroll
    for (int m = 0; m < NM; ++m) acc2[m] = 0.f;

    {
        const float4* cp4 = (const float4*)coefPack;
        int ip = 0, jp = 0;
        float xip = xrow[0];

        float4 A0 = cp4[0], A1 = cp4[1], A2 = cp4[2], A3 = cp4[3];
        float  xiA = xip, xjA = xrow[jp];
        ADV();
        float4 B0 = cp4[4], B1 = cp4[5], B2 = cp4[6], B3 = cp4[7];
        float  xiB = xip, xjB = xrow[jp];
        ADV();
        float4 C0 = cp4[8], C1 = cp4[9], C2 = cp4[10], C3 = cp4[11];
        float  xiC = xip, xjC = xrow[jp];
        ADV();
        cp4 += 12;

        for (int k = 0; k < NPAIR / 3; ++k) {
            float xx = xiA * xjA;
            FMA13(A0, A1, A2, A3, xx);
            A0 = cp4[0]; A1 = cp4[1]; A2 = cp4[2]; A3 = cp4[3];
            xiA = xip; xjA = xrow[jp];
            ADV();

            xx = xiB * xjB;
            FMA13(B0, B1, B2, B3, xx);
            B0 = cp4[4]; B1 = cp4[5]; B2 = cp4[6]; B3 = cp4[7];
            xiB = xip; xjB = xrow[jp];
            ADV();

            xx = xiC * xjC;
            FMA13(C0, C1, C2, C3, xx);
            C0 = cp4[8]; C1 = cp4[9]; C2 = cp4[10]; C3 = cp4[11];
            xiC = xip; xjC = xrow[jp];
            ADV();

            cp4 += 12;
        }
        float xx = xiA * xjA;
        FMA13(A0, A1, A2, A3, xx);
    }

    float basisv[NM];
    basisv[0] = acc1[0] * w1l0 + acc2[0] * w2l0;
    #pragma unroll
    for (int m = 1; m < 4; ++m)  basisv[m] = acc1[m] * w1l1 + acc2[m] * w2l1;
    #pragma unroll
    for (int m = 4; m < NM; ++m) basisv[m] = acc1[m] * w1l2 + acc2[m] * w2l2;

    __syncthreads();
    #pragma unroll
    for (int m = 0; m < NM; ++m)
        xs[m * 64 + c] = basisv[m];
    __syncthreads();

    const int o = c;
    float om[NM];
    #pragma unroll
    for (int m = 0; m < NM; ++m) om[m] = 0.f;

    for (int c4 = 0; c4 < 16; ++c4) {
        const int cc = c4 * 4;
        float p0 = Wlin_0[(cc + 0) * 64 + o], p1 = Wlin_0[(cc + 1) * 64 + o],
              p2 = Wlin_0[(cc + 2) * 64 + o], p3 = Wlin_0[(cc + 3) * 64 + o];
        float q0 = Wlin_1[(cc + 0) * 64 + o], q1 = Wlin_1[(cc + 1) * 64 + o],
              q2 = Wlin_1[(cc + 2) * 64 + o], q3 = Wlin_1[(cc + 3) * 64 + o];
        float r0 = Wlin_2[(cc + 0) * 64 + o], r1 = Wlin_2[(cc + 1) * 64 + o],
              r2 = Wlin_2[(cc + 2) * 64 + o], r3 = Wlin_2[(cc + 3) * 64 + o];

        float4 t;
        t = *(const float4*)&xs[0 * 64 + cc];
        om[0] += t.x * p0 + t.y * p1 + t.z * p2 + t.w * p3;
        #pragma unroll
        for (int m = 1; m < 4; ++m) {
            t = *(const float4*)&xs[m * 64 + cc];
            om[m] += t.x * q0 + t.y * q1 + t.z * q2 + t.w * q3;
        }
        #pragma unroll
        for (int m = 4; m < NM; ++m) {
            t = *(const float4*)&xs[m * 64 + cc];
            om[m] += t.x * r0 + t.y * r1 + t.z * r2 + t.w * r3;
        }
    }

    const int bo = b * 64 + o;
    out[bo] = om[0] + sc_0[bo];
    #pragma unroll
    for (int k = 0; k < 3; ++k)
        out[NB * 64 + bo * 3 + k] = om[1 + k] + sc_1[bo * 3 + k];
    #pragma unroll
    for (int k = 0; k < 9; ++k)
        out[NB * 64 * 4 + bo * 9 + k] = om[4 + k] + sc_2[bo * 9 + k];
}

// ---------------------------------------------------------------------------
extern "C" void kernel_launch(void* const* d_in, const int* in_sizes, int n_in,
                              void* d_out, int out_size, void* d_ws, size_t ws_size,
                              hipStream_t stream) {
    const float* f0    = (const float*)d_in[0];
    const float* f1    = (const float*)d_in[1];
    const float* f2    = (const float*)d_in[2];
    const float* f3    = (const float*)d_in[3];
    const float* attrs = (const float*)d_in[4];
    const float* U2_0  = (const float*)d_in[5];
    const float* U1_0  = (const float*)d_in[6];
    const float* W1_0  = (const float*)d_in[7];
    const float* W2_0  = (const float*)d_in[8];
    const float* Wl_0  = (const float*)d_in[9];
    const float* sc_0  = (const float*)d_in[10];
    const float* U2_1  = (const float*)d_in[11];
    const float* U1_1  = (const float*)d_in[12];
    const float* W1_1  = (const float*)d_in[13];
    const float* W2_1  = (const float*)d_in[14];
    const float* Wl_1  = (const float*)d_in[15];
    const float* sc_1  = (const float*)d_in[16];
    const float* U2_2  = (const float*)d_in[17];
    const float* U1_2  = (const float*)d_in[18];
    const float* W1_2  = (const float*)d_in[19];
    const float* W2_2  = (const float*)d_in[20];
    const float* Wl_2  = (const float*)d_in[21];
    const float* sc_2  = (const float*)d_in[22];
    float* out = (float*)d_out;

    if (ws_size >= WS_NEED_BYTES) {
        // primary: band-4 pack + LDS-tiled transpose + plain-loop main
        float* xT       = (float*)d_ws;
        float* coefPack = xT + XT_FLOATS;
        float* u1Pack   = coefPack + NSTEP4 * 64;

        int packThreads = NSTEP4 * 64 + DIN * 16;
        psc_pack4_kernel<<<(packThreads + 255) / 256, 256, 0, stream>>>(
            U2_0, U2_1, U2_2, U1_0, U1_1, U1_2, coefPack, u1Pack);
        psc_transpose2_kernel<<<NB, 256, 0, stream>>>(f0, f1, f2, f3, xT);
        psc_main_b4<<<NROWS / 256, 128, 0, stream>>>(
            xT, attrs,
            W1_0, W2_0, Wl_0, sc_0,
            W1_1, W2_1, Wl_1, sc_1,
            W1_2, W2_2, Wl_2, sc_2,
            coefPack, u1Pack, out);
    } else {
        // fallback: proven LDS-staged kernel (438 us measured)
        float* coefPack = (float*)d_ws;
        float* u1Pack   = coefPack + NPAIR * 16;

        int packThreads = 1600 * 16 + 40 * 16;
        psc_pack_kernel<<<(packThreads + 255) / 256, 256, 0, stream>>>(
            U2_0, U2_1, U2_2, U1_0, U1_1, U1_2, coefPack, u1Pack);
        psc_main_lds<<<NB, 64, 0, stream>>>(
            f0, f1, f2, f3, attrs,
            W1_0, W2_0, Wl_0, sc_0,
            W1_1, W2_1, Wl_1, sc_1,
            W1_2, W2_2, Wl_2, sc_2,
            coefPack, u1Pack, out);
    }
}

// Round 9
// 607.430 us; speedup vs baseline: 1.0458x; 1.0458x over previous
//
#include <hip/hip_runtime.h>

// Problem constants
#define NB 10000          // batch
#define NC 64             // channels
#define NROWS (NB * NC)   // 640000 (b,c) rows
#define NE 10             // elements
#define DIN 40            // 1+3+9+27
#define NM 13             // 1+3+9 output m's
#define NPAIR 820         // 40*41/2 symmetric pairs (fallback layout)
#define NBAND4 10         // i-bands of 4 (primary layout)
#define NSTEP4 220        // sum_b (40-4b)
#define XS 41             // LDS row stride

#define XT_FLOATS (DIN * NROWS)                       // 25,600,000
#define PACK4_FLOATS (NSTEP4 * 64 + DIN * 16)         // 14,720
#define WS_NEED_BYTES ((size_t)(XT_FLOATS + PACK4_FLOATS) * 4)

// ---------------------------------------------------------------------------
// Pack (primary): band-4 layout. Step e <-> (band b of 4 rows, col j), with
// offset(b) = 2b(21-b), j = 4b + (e - offset(b)), j in [4b, 39].
// Entry = 64 floats: 4 pair-slots x 16; slot t holds coefs for pair
// (i=4b+t, j), x2 off-diagonal, ZERO when i>j or m>=13.  u1Pack [40][16]
// follows (layout unchanged).
// ---------------------------------------------------------------------------
__global__ void psc_pack4_kernel(const float* __restrict__ U2_0,
                                 const float* __restrict__ U2_1,
                                 const float* __restrict__ U2_2,
                                 const float* __restrict__ U1_0,
                                 const float* __restrict__ U1_1,
                                 const float* __restrict__ U1_2,
                                 float* __restrict__ coefPack,   // [220][64]
                                 float* __restrict__ u1Pack)     // [40][16]
{
    int tid = blockIdx.x * blockDim.x + threadIdx.x;
    if (tid < NSTEP4 * 64) {
        int e = tid >> 6, s = tid & 63;
        int t = s >> 4, m = s & 15;
        int b = 0;
        while (b < NBAND4 - 1 && 2 * (b + 1) * (20 - b) <= e) ++b;
        int j = 4 * b + (e - 2 * b * (21 - b));
        int i = 4 * b + t;
        float v = 0.0f;
        if (m < NM && i <= j && j < DIN) {
            float sc = (i == j) ? 1.0f : 2.0f;
            if (m == 0)      v = U2_0[i * 40 + j] * sc;
            else if (m < 4)  v = U2_1[(m - 1) * 1600 + i * 40 + j] * sc;
            else             v = U2_2[(m - 4) * 1600 + i * 40 + j] * sc;
        }
        coefPack[tid] = v;
    } else if (tid < NSTEP4 * 64 + DIN * 16) {
        int t = tid - NSTEP4 * 64;
        int m = t & 15;
        int i = t >> 4;
        float v = 0.0f;
        if (m == 0)       v = U1_0[i];
        else if (m < 4)   v = U1_1[(m - 1) * 40 + i];
        else if (m < 13)  v = U1_2[(m - 4) * 40 + i];
        u1Pack[i * 16 + m] = v;
    }
}

// ---------------------------------------------------------------------------
// Transpose (primary): LDS-tiled, coalesced reads AND writes.
// ---------------------------------------------------------------------------
__global__ __launch_bounds__(256)
void psc_transpose2_kernel(const float* __restrict__ f0,
                           const float* __restrict__ f1,
                           const float* __restrict__ f2,
                           const float* __restrict__ f3,
                           float* __restrict__ xT)
{
    __shared__ float ls[64 * XS];     // 10.5 KB
    const int t = threadIdx.x;
    const int b = blockIdx.x;

    if (t < 64)  ls[t * XS + 0] = f0[b * 64 + t];
    if (t < 192) { int c = t / 3, k = t % 3; ls[c * XS + 1 + k] = f1[b * 192 + t]; }
    for (int idx = t; idx < 576; idx += 256) {
        int c = idx / 9, k = idx % 9;
        ls[c * XS + 4 + k] = f2[b * 576 + idx];
    }
    for (int idx = t; idx < 1728; idx += 256) {
        int c = idx / 27, k = idx % 27;
        ls[c * XS + 13 + k] = f3[b * 1728 + idx];
    }
    __syncthreads();

    const int c = t & 63, j0 = t >> 6;
    #pragma unroll
    for (int jj = 0; jj < 10; ++jj) {
        int j = j0 + jj * 4;
        xT[j * NROWS + b * 64 + c] = ls[c * XS + j];   // stride-41: conflict-free
    }
}

// 13 FMAs into acc2[R][*] from 4 float4 coefficient regs (wave-uniform)
#define FMA13Q(R, Q0, Q1, Q2, Q3, XX)                                   \
    acc2[R][0]  += (Q0).x * (XX);  acc2[R][1]  += (Q0).y * (XX);        \
    acc2[R][2]  += (Q0).z * (XX);  acc2[R][3]  += (Q0).w * (XX);        \
    acc2[R][4]  += (Q1).x * (XX);  acc2[R][5]  += (Q1).y * (XX);        \
    acc2[R][6]  += (Q1).z * (XX);  acc2[R][7]  += (Q1).w * (XX);        \
    acc2[R][8]  += (Q2).x * (XX);  acc2[R][9]  += (Q2).y * (XX);        \
    acc2[R][10] += (Q2).z * (XX);  acc2[R][11] += (Q2).w * (XX);        \
    acc2[R][12] += (Q3).x * (XX);

#define A1FMA(R, Q0, Q1, Q2, Q3, XI)                                    \
    a1[R][0]  += (Q0).x * (XI);  a1[R][1]  += (Q0).y * (XI);            \
    a1[R][2]  += (Q0).z * (XI);  a1[R][3]  += (Q0).w * (XI);            \
    a1[R][4]  += (Q1).x * (XI);  a1[R][5]  += (Q1).y * (XI);            \
    a1[R][6]  += (Q1).z * (XI);  a1[R][7]  += (Q1).w * (XI);            \
    a1[R][8]  += (Q2).x * (XI);  a1[R][9]  += (Q2).y * (XI);            \
    a1[R][10] += (Q2).z * (XI);  a1[R][11] += (Q2).w * (XI);            \
    a1[R][12] += (Q3).x * (XI);

// ---------------------------------------------------------------------------
// Main (primary): band-4, plain rolled loop, fused per-row epilogue.
// Block = 128 threads = 2 waves; wave owns 128 rows (2 b's, R=2 rows/lane).
// __launch_bounds__(128, 4): VGPR cap 128 -- fits the ~90 live floats
// (52 accumulators + band xi/xj + addresses) WITHOUT spilling. R8's (128,6)
// capped at 85 -> VGPR=40 + scratch spills (+22.5 MB WRITE_SIZE, VALU x1.7).
// ---------------------------------------------------------------------------
__global__ __launch_bounds__(128, 4)
void psc_main_b4(const float* __restrict__ xT,
                 const float* __restrict__ attrs,
                 const float* __restrict__ W1_0, const float* __restrict__ W2_0,
                 const float* __restrict__ Wlin_0, const float* __restrict__ sc_0,
                 const float* __restrict__ W1_1, const float* __restrict__ W2_1,
                 const float* __restrict__ Wlin_1, const float* __restrict__ sc_1,
                 const float* __restrict__ W1_2, const float* __restrict__ W2_2,
                 const float* __restrict__ Wlin_2, const float* __restrict__ sc_2,
                 const float* __restrict__ coefPack,
                 const float* __restrict__ u1Pack,
                 float* __restrict__ out)
{
    __shared__ float bsT[2][NM][64];          // per-wave row buffer, 6656 B

    const int lane = threadIdx.x & 63;
    const int wid  = threadIdx.x >> 6;
    const int bc0  = blockIdx.x * 256 + wid * 128;  // wave's first row

    float acc2[2][NM], a1[2][NM];
    #pragma unroll
    for (int m = 0; m < NM; ++m) {
        acc2[0][m] = 0.f; acc2[1][m] = 0.f;
        a1[0][m] = 0.f;   a1[1][m] = 0.f;
    }

    const float4* cp4 = (const float4*)coefPack;
    const float4* u14 = (const float4*)u1Pack;

    for (int b4 = 0; b4 < NBAND4; ++b4) {
        const int i0 = 4 * b4;

        // band xi registers (4 i-rows x 2 b-rows)
        const float* xip = xT + i0 * NROWS + bc0;
        float xi00 = xip[lane], xi01 = xip[lane + 64]; xip += NROWS;
        float xi10 = xip[lane], xi11 = xip[lane + 64]; xip += NROWS;
        float xi20 = xip[lane], xi21 = xip[lane + 64]; xip += NROWS;
        float xi30 = xip[lane], xi31 = xip[lane + 64];

        // fold a1 for this band's 4 i-rows (uniform u1 loads)
        {
            const float4* u = u14 + i0 * 4;
            float4 u0 = u[0],  u1 = u[1],  u2 = u[2],  u3 = u[3];
            A1FMA(0, u0, u1, u2, u3, xi00);  A1FMA(1, u0, u1, u2, u3, xi01);
            u0 = u[4];  u1 = u[5];  u2 = u[6];  u3 = u[7];
            A1FMA(0, u0, u1, u2, u3, xi10);  A1FMA(1, u0, u1, u2, u3, xi11);
            u0 = u[8];  u1 = u[9];  u2 = u[10]; u3 = u[11];
            A1FMA(0, u0, u1, u2, u3, xi20);  A1FMA(1, u0, u1, u2, u3, xi21);
            u0 = u[12]; u1 = u[13]; u2 = u[14]; u3 = u[15];
            A1FMA(0, u0, u1, u2, u3, xi30);  A1FMA(1, u0, u1, u2, u3, xi31);
        }

        // inner j loop: plain, compiler-scheduled
        const float* xjp = xT + i0 * NROWS + bc0;
        for (int j = i0; j < DIN; ++j) {
            float xj0 = xjp[lane];
            float xj1 = xjp[lane + 64];
            xjp += NROWS;
            float4 q0  = cp4[0],  q1  = cp4[1],  q2  = cp4[2],  q3  = cp4[3];
            float4 q4  = cp4[4],  q5  = cp4[5],  q6  = cp4[6],  q7  = cp4[7];
            float4 q8  = cp4[8],  q9  = cp4[9],  q10 = cp4[10], q11 = cp4[11];
            float4 q12 = cp4[12], q13 = cp4[13], q14 = cp4[14], q15 = cp4[15];
            cp4 += 16;

            float xx00 = xi00 * xj0, xx01 = xi01 * xj1;
            float xx10 = xi10 * xj0, xx11 = xi11 * xj1;
            float xx20 = xi20 * xj0, xx21 = xi21 * xj1;
            float xx30 = xi30 * xj0, xx31 = xi31 * xj1;

            FMA13Q(0, q0,  q1,  q2,  q3,  xx00);
            FMA13Q(1, q0,  q1,  q2,  q3,  xx01);
            FMA13Q(0, q4,  q5,  q6,  q7,  xx10);
            FMA13Q(1, q4,  q5,  q6,  q7,  xx11);
            FMA13Q(0, q8,  q9,  q10, q11, xx20);
            FMA13Q(1, q8,  q9,  q10, q11, xx21);
            FMA13Q(0, q12, q13, q14, q15, xx30);
            FMA13Q(1, q12, q13, q14, q15, xx31);
        }
    }

    // ---- per-row epilogue: w-weights, basis -> per-wave LDS, mix, write ----
    #pragma unroll
    for (int r = 0; r < 2; ++r) {
        const int br = (bc0 >> 6) + r;

        float w10 = 0.f, w20 = 0.f, w11 = 0.f, w21 = 0.f, w12 = 0.f, w22 = 0.f;
        #pragma unroll
        for (int e = 0; e < NE; ++e) {
            float av = attrs[br * NE + e];       // wave-uniform -> s_load
            w10 += av * W1_0[e * 64 + lane];
            w20 += av * W2_0[e * 64 + lane];
            w11 += av * W1_1[e * 64 + lane];
            w21 += av * W2_1[e * 64 + lane];
            w12 += av * W1_2[e * 64 + lane];
            w22 += av * W2_2[e * 64 + lane];
        }

        bsT[wid][0][lane] = a1[r][0] * w10 + acc2[r][0] * w20;
        #pragma unroll
        for (int m = 1; m < 4; ++m)
            bsT[wid][m][lane] = a1[r][m] * w11 + acc2[r][m] * w21;
        #pragma unroll
        for (int m = 4; m < NM; ++m)
            bsT[wid][m][lane] = a1[r][m] * w12 + acc2[r][m] * w22;
        // wave-private buffer: in-order DS pipe + compiler lgkmcnt, no barrier

        float om[NM];
        #pragma unroll
        for (int m = 0; m < NM; ++m) om[m] = 0.f;

        for (int c4 = 0; c4 < 16; ++c4) {
            const int cc = c4 * 4;
            float p0 = Wlin_0[(cc + 0) * 64 + lane], p1 = Wlin_0[(cc + 1) * 64 + lane],
                  p2 = Wlin_0[(cc + 2) * 64 + lane], p3 = Wlin_0[(cc + 3) * 64 + lane];
            float q0 = Wlin_1[(cc + 0) * 64 + lane], q1 = Wlin_1[(cc + 1) * 64 + lane],
                  q2 = Wlin_1[(cc + 2) * 64 + lane], q3 = Wlin_1[(cc + 3) * 64 + lane];
            float r0 = Wlin_2[(cc + 0) * 64 + lane], r1 = Wlin_2[(cc + 1) * 64 + lane],
                  r2 = Wlin_2[(cc + 2) * 64 + lane], r3 = Wlin_2[(cc + 3) * 64 + lane];

            float4 tv;
            tv = *(const float4*)&bsT[wid][0][cc];   // uniform -> broadcast
            om[0] += tv.x * p0 + tv.y * p1 + tv.z * p2 + tv.w * p3;
            #pragma unroll
            for (int m = 1; m < 4; ++m) {
                tv = *(const float4*)&bsT[wid][m][cc];
                om[m] += tv.x * q0 + tv.y * q1 + tv.z * q2 + tv.w * q3;
            }
            #pragma unroll
            for (int m = 4; m < NM; ++m) {
                tv = *(const float4*)&bsT[wid][m][cc];
                om[m] += tv.x * r0 + tv.y * r1 + tv.z * r2 + tv.w * r3;
            }
        }

        const int bo = bc0 + r * 64 + lane;     // == b*64 + c
        out[bo] = om[0] + sc_0[bo];
        #pragma unroll
        for (int k = 0; k < 3; ++k)
            out[NROWS + bo * 3 + k] = om[1 + k] + sc_1[bo * 3 + k];
        #pragma unroll
        for (int k = 0; k < 9; ++k)
            out[NROWS * 4 + bo * 9 + k] = om[4 + k] + sc_2[bo * 9 + k];
    }
}

// ---------------------------------------------------------------------------
// Fallback path (proven 438 us, measured R4): old pack layout + LDS-staged x.
// ---------------------------------------------------------------------------
__global__ void psc_pack_kernel(const float* __restrict__ U2_0,
                                const float* __restrict__ U2_1,
                                const float* __restrict__ U2_2,
                                const float* __restrict__ U1_0,
                                const float* __restrict__ U1_1,
                                const float* __restrict__ U1_2,
                                float* __restrict__ coefPack,   // [820][16]
                                float* __restrict__ u1Pack)     // [40][16]
{
    int tid = blockIdx.x * blockDim.x + threadIdx.x;
    if (tid < 1600 * 16) {
        int m = tid & 15;
        int idx = tid >> 4;
        int i = idx / 40, j = idx % 40;
        if (j < i) return;
        int p = i * 40 - ((i * (i - 1)) >> 1) + (j - i);
        float s = (i == j) ? 1.0f : 2.0f;
        float v = 0.0f;
        if (m == 0)       v = U2_0[i * 40 + j];
        else if (m < 4)   v = U2_1[(m - 1) * 1600 + i * 40 + j];
        else if (m < 13)  v = U2_2[(m - 4) * 1600 + i * 40 + j];
        coefPack[p * 16 + m] = v * s;
    } else if (tid < 1600 * 16 + 40 * 16) {
        int t = tid - 1600 * 16;
        int m = t & 15;
        int i = t >> 4;
        float v = 0.0f;
        if (m == 0)       v = U1_0[i];
        else if (m < 4)   v = U1_1[(m - 1) * 40 + i];
        else if (m < 13)  v = U1_2[(m - 4) * 40 + i];
        u1Pack[i * 16 + m] = v;
    }
}

#define FMA13(Q0, Q1, Q2, Q3, XX)                                     \
    acc2[0]  += (Q0).x * (XX);  acc2[1]  += (Q0).y * (XX);            \
    acc2[2]  += (Q0).z * (XX);  acc2[3]  += (Q0).w * (XX);            \
    acc2[4]  += (Q1).x * (XX);  acc2[5]  += (Q1).y * (XX);            \
    acc2[6]  += (Q1).z * (XX);  acc2[7]  += (Q1).w * (XX);            \
    acc2[8]  += (Q2).x * (XX);  acc2[9]  += (Q2).y * (XX);            \
    acc2[10] += (Q2).z * (XX);  acc2[11] += (Q2).w * (XX);            \
    acc2[12] += (Q3).x * (XX);

#define ADV()                                                         \
    do {                                                              \
        ++jp;                                                         \
        if (jp >= DIN) {                                              \
            if (ip < DIN - 1) ++ip;                                   \
            jp = ip;                                                  \
            xip = xrow[ip];                                           \
        }                                                             \
    } while (0)

__global__ __launch_bounds__(64, 4)
void psc_main_lds(const float* __restrict__ f0, const float* __restrict__ f1,
                  const float* __restrict__ f2, const float* __restrict__ f3,
                  const float* __restrict__ attrs,
                  const float* __restrict__ W1_0, const float* __restrict__ W2_0,
                  const float* __restrict__ Wlin_0, const float* __restrict__ sc_0,
                  const float* __restrict__ W1_1, const float* __restrict__ W2_1,
                  const float* __restrict__ Wlin_1, const float* __restrict__ sc_1,
                  const float* __restrict__ W1_2, const float* __restrict__ W2_2,
                  const float* __restrict__ Wlin_2, const float* __restrict__ sc_2,
                  const float* __restrict__ coefPack,
                  const float* __restrict__ u1Pack,
                  float* __restrict__ out)
{
    __shared__ float xs[64 * XS];

    const int c = threadIdx.x;
    const int b = blockIdx.x;

    xs[c * XS + 0] = f0[b * 64 + c];
    #pragma unroll
    for (int t = 0; t < 3; ++t) {
        int idx = c + 64 * t;
        int cc = idx / 3, k = idx % 3;
        xs[cc * XS + 1 + k] = f1[b * 192 + idx];
    }
    #pragma unroll
    for (int t = 0; t < 9; ++t) {
        int idx = c + 64 * t;
        int cc = idx / 9, k = idx % 9;
        xs[cc * XS + 4 + k] = f2[b * 576 + idx];
    }
    #pragma unroll
    for (int t = 0; t < 27; ++t) {
        int idx = c + 64 * t;
        int cc = idx / 27, k = idx % 27;
        xs[cc * XS + 13 + k] = f3[b * 1728 + idx];
    }
    __syncthreads();

    float w1l0 = 0.f, w2l0 = 0.f, w1l1 = 0.f, w2l1 = 0.f, w1l2 = 0.f, w2l2 = 0.f;
    #pragma unroll
    for (int e = 0; e < NE; ++e) {
        float a = attrs[b * NE + e];
        w1l0 += a * W1_0[e * 64 + c];
        w2l0 += a * W2_0[e * 64 + c];
        w1l1 += a * W1_1[e * 64 + c];
        w2l1 += a * W2_1[e * 64 + c];
        w1l2 += a * W1_2[e * 64 + c];
        w2l2 += a * W2_2[e * 64 + c];
    }

    const float* xrow = &xs[c * XS];

    float acc1[NM];
    #pragma unroll
    for (int m = 0; m < NM; ++m) acc1[m] = 0.f;
    #pragma unroll 4
    for (int i = 0; i < DIN; ++i) {
        float xi = xrow[i];
        const float4* u4 = (const float4*)&u1Pack[i * 16];
        float4 u0 = u4[0], u1v = u4[1], u2v = u4[2], u3v = u4[3];
        acc1[0]  += u0.x  * xi;  acc1[1]  += u0.y  * xi;
        acc1[2]  += u0.z  * xi;  acc1[3]  += u0.w  * xi;
        acc1[4]  += u1v.x * xi;  acc1[5]  += u1v.y * xi;
        acc1[6]  += u1v.z * xi;  acc1[7]  += u1v.w * xi;
        acc1[8]  += u2v.x * xi;  acc1[9]  += u2v.y * xi;
        acc1[10] += u2v.z * xi;  acc1[11] += u2v.w * xi;
        acc1[12] += u3v.x * xi;
    }

    float acc2[NM];
    #pragma unroll
    for (int m = 0; m < NM; ++m) acc2[m] = 0.f;

    {
        const float4* cp4 = (const float4*)coefPack;
        int ip = 0, jp = 0;
        float xip = xrow[0];

        float4 A0 = cp4[0], A1 = cp4[1], A2 = cp4[2], A3 = cp4[3];
        float  xiA = xip, xjA = xrow[jp];
        ADV();
        float4 B0 = cp4[4], B1 = cp4[5], B2 = cp4[6], B3 = cp4[7];
        float  xiB = xip, xjB = xrow[jp];
        ADV();
        float4 C0 = cp4[8], C1 = cp4[9], C2 = cp4[10], C3 = cp4[11];
        float  xiC = xip, xjC = xrow[jp];
        ADV();
        cp4 += 12;

        for (int k = 0; k < NPAIR / 3; ++k) {
            float xx = xiA * xjA;
            FMA13(A0, A1, A2, A3, xx);
            A0 = cp4[0]; A1 = cp4[1]; A2 = cp4[2]; A3 = cp4[3];
            xiA = xip; xjA = xrow[jp];
            ADV();

            xx = xiB * xjB;
            FMA13(B0, B1, B2, B3, xx);
            B0 = cp4[4]; B1 = cp4[5]; B2 = cp4[6]; B3 = cp4[7];
            xiB = xip; xjB = xrow[jp];
            ADV();

            xx = xiC * xjC;
            FMA13(C0, C1, C2, C3, xx);
            C0 = cp4[8]; C1 = cp4[9]; C2 = cp4[10]; C3 = cp4[11];
            xiC = xip; xjC = xrow[jp];
            ADV();

            cp4 += 12;
        }
        float xx = xiA * xjA;
        FMA13(A0, A1, A2, A3, xx);
    }

    float basisv[NM];
    basisv[0] = acc1[0] * w1l0 + acc2[0] * w2l0;
    #pragma unroll
    for (int m = 1; m < 4; ++m)  basisv[m] = acc1[m] * w1l1 + acc2[m] * w2l1;
    #pragma unroll
    for (int m = 4; m < NM; ++m) basisv[m] = acc1[m] * w1l2 + acc2[m] * w2l2;

    __syncthreads();
    #pragma unroll
    for (int m = 0; m < NM; ++m)
        xs[m * 64 + c] = basisv[m];
    __syncthreads();

    const int o = c;
    float om[NM];
    #pragma unroll
    for (int m = 0; m < NM; ++m) om[m] = 0.f;

    for (int c4 = 0; c4 < 16; ++c4) {
        const int cc = c4 * 4;
        float p0 = Wlin_0[(cc + 0) * 64 + o], p1 = Wlin_0[(cc + 1) * 64 + o],
              p2 = Wlin_0[(cc + 2) * 64 + o], p3 = Wlin_0[(cc + 3) * 64 + o];
        float q0 = Wlin_1[(cc + 0) * 64 + o], q1 = Wlin_1[(cc + 1) * 64 + o],
              q2 = Wlin_1[(cc + 2) * 64 + o], q3 = Wlin_1[(cc + 3) * 64 + o];
        float r0 = Wlin_2[(cc + 0) * 64 + o], r1 = Wlin_2[(cc + 1) * 64 + o],
              r2 = Wlin_2[(cc + 2) * 64 + o], r3 = Wlin_2[(cc + 3) * 64 + o];

        float4 t;
        t = *(const float4*)&xs[0 * 64 + cc];
        om[0] += t.x * p0 + t.y * p1 + t.z * p2 + t.w * p3;
        #pragma unroll
        for (int m = 1; m < 4; ++m) {
            t = *(const float4*)&xs[m * 64 + cc];
            om[m] += t.x * q0 + t.y * q1 + t.z * q2 + t.w * q3;
        }
        #pragma unroll
        for (int m = 4; m < NM; ++m) {
            t = *(const float4*)&xs[m * 64 + cc];
            om[m] += t.x * r0 + t.y * r1 + t.z * r2 + t.w * r3;
        }
    }

    const int bo = b * 64 + o;
    out[bo] = om[0] + sc_0[bo];
    #pragma unroll
    for (int k = 0; k < 3; ++k)
        out[NB * 64 + bo * 3 + k] = om[1 + k] + sc_1[bo * 3 + k];
    #pragma unroll
    for (int k = 0; k < 9; ++k)
        out[NB * 64 * 4 + bo * 9 + k] = om[4 + k] + sc_2[bo * 9 + k];
}

// ---------------------------------------------------------------------------
extern "C" void kernel_launch(void* const* d_in, const int* in_sizes, int n_in,
                              void* d_out, int out_size, void* d_ws, size_t ws_size,
                              hipStream_t stream) {
    const float* f0    = (const float*)d_in[0];
    const float* f1    = (const float*)d_in[1];
    const float* f2    = (const float*)d_in[2];
    const float* f3    = (const float*)d_in[3];
    const float* attrs = (const float*)d_in[4];
    const float* U2_0  = (const float*)d_in[5];
    const float* U1_0  = (const float*)d_in[6];
    const float* W1_0  = (const float*)d_in[7];
    const float* W2_0  = (const float*)d_in[8];
    const float* Wl_0  = (const float*)d_in[9];
    const float* sc_0  = (const float*)d_in[10];
    const float* U2_1  = (const float*)d_in[11];
    const float* U1_1  = (const float*)d_in[12];
    const float* W1_1  = (const float*)d_in[13];
    const float* W2_1  = (const float*)d_in[14];
    const float* Wl_1  = (const float*)d_in[15];
    const float* sc_1  = (const float*)d_in[16];
    const float* U2_2  = (const float*)d_in[17];
    const float* U1_2  = (const float*)d_in[18];
    const float* W1_2  = (const float*)d_in[19];
    const float* W2_2  = (const float*)d_in[20];
    const float* Wl_2  = (const float*)d_in[21];
    const float* sc_2  = (const float*)d_in[22];
    float* out = (float*)d_out;

    if (ws_size >= WS_NEED_BYTES) {
        // primary: band-4 pack + LDS-tiled transpose + plain-loop main
        float* xT       = (float*)d_ws;
        float* coefPack = xT + XT_FLOATS;
        float* u1Pack   = coefPack + NSTEP4 * 64;

        int packThreads = NSTEP4 * 64 + DIN * 16;
        psc_pack4_kernel<<<(packThreads + 255) / 256, 256, 0, stream>>>(
            U2_0, U2_1, U2_2, U1_0, U1_1, U1_2, coefPack, u1Pack);
        psc_transpose2_kernel<<<NB, 256, 0, stream>>>(f0, f1, f2, f3, xT);
        psc_main_b4<<<NROWS / 256, 128, 0, stream>>>(
            xT, attrs,
            W1_0, W2_0, Wl_0, sc_0,
            W1_1, W2_1, Wl_1, sc_1,
            W1_2, W2_2, Wl_2, sc_2,
            coefPack, u1Pack, out);
    } else {
        // fallback: proven LDS-staged kernel (438 us measured)
        float* coefPack = (float*)d_ws;
        float* u1Pack   = coefPack + NPAIR * 16;

        int packThreads = 1600 * 16 + 40 * 16;
        psc_pack_kernel<<<(packThreads + 255) / 256, 256, 0, stream>>>(
            U2_0, U2_1, U2_2, U1_0, U1_1, U1_2, coefPack, u1Pack);
        psc_main_lds<<<NB, 64, 0, stream>>>(
            f0, f1, f2, f3, attrs,
            W1_0, W2_0, Wl_0, sc_0,
            W1_1, W2_1, Wl_1, sc_1,
            W1_2, W2_2, Wl_2, sc_2,
            coefPack, u1Pack, out);
    }
}